// Round 6
// baseline (741.888 us; speedup 1.0000x reference)
//
#include <hip/hip_runtime.h>
#include <hip/hip_bf16.h>

#define BB 512
#define NA 58
#define LAT 64
#define HID 128
#define AF 10
#define NL 2
#define NN (BB*NA)      // 29696
#define NE (NN*16)      // 475136
#define ET 64           // edges per tile
#define NTILE (NE/ET)   // 7424
#define PBLK 1024       // persistent blocks (4 per CU)

typedef __attribute__((ext_vector_type(8))) short s8;
typedef __attribute__((ext_vector_type(4))) float f4;

struct CvtDesc {
    const void* src[24];
    float*      dst[24];
    int         len[24];
};

struct PackJobs {
    const float* src[10];
    short*       dst[10];
    int          K[10];
    int          mode[10];   // 0 = plain pack, 1 = edge-w1 concat pack
};

__device__ __forceinline__ float siluf(float x) {
    // x * sigmoid(x) with fast rcp (v_rcp_f32, ~1ulp - fine for bf16 outputs)
    return x * __builtin_amdgcn_rcpf(1.0f + __expf(-x));
}

__device__ __forceinline__ short f2b(float x) {
    __hip_bfloat16 b = __float2bfloat16(x);
    return *(short*)&b;
}

__device__ __forceinline__ float b2f(short s) {
    return __uint_as_float(((unsigned int)(unsigned short)s) << 16);
}

// ---------------------------------------------------------------------------
__global__ void k_detect(const unsigned short* __restrict__ z16,
                         const unsigned int* __restrict__ e32,
                         int* __restrict__ flags) {
    __shared__ int sbf, si64;
    if (threadIdx.x == 0) { sbf = 0; si64 = 0; }
    __syncthreads();
    int c1 = 0, c2 = 0;
    for (int i = threadIdx.x; i < 1024; i += 256) {
        unsigned short v = z16[2*i];
        int e = (v >> 7) & 0xFF;
        if (e >= 100 && e <= 140) c1++;
        if (e32[2*i + 1] == 0u) c2++;
    }
    atomicAdd(&sbf, c1);
    atomicAdd(&si64, c2);
    __syncthreads();
    if (threadIdx.x == 0) {
        flags[0] = (sbf  > 600) ? 1 : 0;
        flags[1] = (si64 > 600) ? 1 : 0;
    }
}

__global__ void k_convert(CvtDesc d, const int* __restrict__ flags) {
    int a = blockIdx.y;
    int i = blockIdx.x * blockDim.x + threadIdx.x;
    int n = d.len[a];
    if (i >= n) return;
    if (flags[0]) {
        d.dst[a][i] = __bfloat162float(((const __hip_bfloat16*)d.src[a])[i]);
    } else {
        d.dst[a][i] = ((const float*)d.src[a])[i];
    }
}

// All weight packs in one launch. mode 0: [K][128] -> B-frag; mode 1: edge w1
// rows 0..255 as K=128,N=256 concat tensor.
__global__ void k_packall(PackJobs pj) {
    int j = blockIdx.y;
    int idx = blockIdx.x * 256 + threadIdx.x;
    const float* w = pj.src[j];
    short* o = pj.dst[j];
    if (pj.mode[j] == 0) {
        int K = pj.K[j];
        if (idx >= 128*K) return;
        int jj = idx & 7;
        int l  = (idx >> 3) & 63;
        int rest = idx >> 9;
        int KC = K >> 5;
        int kc = rest % KC;
        int nt = rest / KC;
        int n = nt*16 + (l & 15);
        int k = kc*32 + (l >> 4)*8 + jj;
        o[idx] = f2b(w[k*128 + n]);
    } else {
        if (idx >= 32768) return;
        int jj = idx & 7;
        int l  = (idx >> 3) & 63;
        int rest = idx >> 9;
        int kc = rest & 3;
        int nt = rest >> 2;
        int n = nt*16 + (l & 15);
        int k = kc*32 + (l >> 4)*8 + jj;
        float v = (n < 128) ? w[k*128 + n] : w[(128 + k)*128 + (n - 128)];
        o[idx] = f2b(v);
    }
}

// ---------------------------------------------------------------------------
// counting sort of edges by row
__global__ void k_zero_cnt(int* __restrict__ cnt) {
    int i = blockIdx.x * 256 + threadIdx.x;
    if (i < NN) cnt[i] = 0;
}

__global__ void k_hist(const int* __restrict__ eidx, const int* __restrict__ flags,
                       int* __restrict__ cnt) {
    int e = blockIdx.x * 256 + threadIdx.x;
    if (e >= NE) return;
    int is64 = flags[1];
    int r = eidx[is64 ? 2*(long)e : (long)e];
    atomicAdd(&cnt[r], 1);
}

__global__ __launch_bounds__(1024) void k_scan(const int* __restrict__ cnt,
                                               int* __restrict__ rowStart,
                                               int* __restrict__ cursor) {
    __shared__ int part[1024];
    int t = threadIdx.x;
    int base = t * 29;                    // NN == 1024*29
    int loc[29];
    int s = 0;
    #pragma unroll
    for (int i = 0; i < 29; ++i) { loc[i] = s; s += cnt[base + i]; }
    part[t] = s;
    __syncthreads();
    for (int d = 1; d < 1024; d <<= 1) {
        int v = (t >= d) ? part[t - d] : 0;
        __syncthreads();
        part[t] += v;
        __syncthreads();
    }
    int pre = (t == 0) ? 0 : part[t - 1];
    #pragma unroll
    for (int i = 0; i < 29; ++i) {
        int v = pre + loc[i];
        rowStart[base + i] = v;
        cursor[base + i] = v;
    }
    if (t == 1023) rowStart[NN] = pre + s;
}

__global__ void k_scatter(const int* __restrict__ eidx, const int* __restrict__ flags,
                          int* __restrict__ cursor,
                          int* __restrict__ rS, int* __restrict__ cS) {
    int e = blockIdx.x * 256 + threadIdx.x;
    if (e >= NE) return;
    int is64 = flags[1];
    long ge = e, gc = (long)e + NE;
    int r = eidx[is64 ? 2*ge : ge];
    int c = eidx[is64 ? 2*gc : gc];
    int p = atomicAdd(&cursor[r], 1);
    rS[p] = r; cS[p] = c;
}

// ---------------------------------------------------------------------------
__global__ void k_hz(const float* __restrict__ z, const float* __restrict__ lw,
                     const float* __restrict__ lb, float* __restrict__ hz) {
    __shared__ float zs[LAT];
    int b = blockIdx.x;
    int c = threadIdx.x;
    if (c < LAT) zs[c] = z[b*LAT + c];
    __syncthreads();
    float acc = lb[c];
    #pragma unroll
    for (int k = 0; k < LAT; ++k) acc += zs[k] * lw[k*HID + c];
    hz[b*HID + c] = acc;
}

// fused: h init (bf16 only) + pos init
__global__ void k_init2(const float* __restrict__ hz, const float* __restrict__ at,
                        const float* __restrict__ aw, const float* __restrict__ ab,
                        const float* __restrict__ ic,
                        float* __restrict__ pos, short* __restrict__ hb) {
    __shared__ float ats[AF];
    int n = blockIdx.x;
    int c = threadIdx.x;
    int b = n / NA;
    if (c < AF) ats[c] = at[n*AF + c];
    __syncthreads();
    float acc = hz[b*HID + c] + ab[c];
    #pragma unroll
    for (int f = 0; f < AF; ++f) acc += ats[f] * aw[f*HID + c];
    hb[(long)n*HID + c] = f2b(acc);
    if (c < 3) {
        int a = n % NA;
        pos[n*3 + c] = ic[a*3 + c];
    }
}

__global__ void k_zero(float* __restrict__ agg, float* __restrict__ upd) {
    int i = blockIdx.x * blockDim.x + threadIdx.x;
    if (i < NN*HID) agg[i] = 0.f;
    if (i < NN*3)   upd[i] = 0.f;
}

// ---------------------------------------------------------------------------
// H1 = hb @ [w1a|w1b] (+ b1 on a-half) -> [NN][256] bf16.
__global__ __launch_bounds__(256) void k_pre(
    const short* __restrict__ hb, const short* __restrict__ wcat,
    const float* __restrict__ b1, short* __restrict__ H1)
{
    __shared__ short x[64][136];
    const int tid = threadIdx.x;
    const int n0 = blockIdx.x * 64;

    #pragma unroll
    for (int it = 0; it < 4; ++it) {
        int idx = it*256 + tid;
        int e = idx >> 4, q = idx & 15;
        *(int4*)&x[e][q*8] = *(const int4*)(hb + (long)(n0+e)*HID + q*8);
    }
    __syncthreads();

    const int l = tid & 63, w = tid >> 6;
    const int l16 = l & 15, quad = l >> 4;

    f4 acc[4][4];
    #pragma unroll
    for (int mt = 0; mt < 4; ++mt)
        #pragma unroll
        for (int nt4 = 0; nt4 < 4; ++nt4) acc[mt][nt4] = (f4)0.f;

    #pragma unroll
    for (int kc = 0; kc < 4; ++kc) {
        s8 a[4];
        #pragma unroll
        for (int mt = 0; mt < 4; ++mt)
            a[mt] = *(const s8*)&x[mt*16 + l16][kc*32 + quad*8];
        #pragma unroll
        for (int nt4 = 0; nt4 < 4; ++nt4) {
            int nt = w*4 + nt4;
            s8 b = *(const s8*)(wcat + (((size_t)nt*4 + kc)*64 + l)*8);
            #pragma unroll
            for (int mt = 0; mt < 4; ++mt)
                acc[mt][nt4] = __builtin_amdgcn_mfma_f32_16x16x32_bf16(a[mt], b, acc[mt][nt4], 0, 0, 0);
        }
    }
    #pragma unroll
    for (int nt4 = 0; nt4 < 4; ++nt4) {
        int col = (w*4 + nt4)*16 + l16;
        float bias = (col < 128) ? b1[col] : 0.f;
        #pragma unroll
        for (int mt = 0; mt < 4; ++mt)
            #pragma unroll
            for (int i = 0; i < 4; ++i) {
                int row = mt*16 + quad*4 + i;
                H1[(long)(n0 + row)*256 + col] = f2b(acc[mt][nt4][i] + bias);
            }
    }
}

// ---------------------------------------------------------------------------
// Edge kernel v3: per-wave meta+gather prefetch straight into A-frag channels.
__global__ __launch_bounds__(256, 4) void k_edge3(
    const short* __restrict__ H1, const float* __restrict__ pos,
    const int* __restrict__ rS, const int* __restrict__ cS,
    const float* __restrict__ w1c,
    const short* __restrict__ w2p, const float* __restrict__ b2,
    const short* __restrict__ c1p, const float* __restrict__ cb1,
    const float* __restrict__ cw2,
    float* __restrict__ agg, float* __restrict__ upd)
{
    __shared__ short t1[ET][136];
    __shared__ short mm[ET][136];
    __shared__ int   rIs[ET];
    __shared__ float relS[ET][3];
    __shared__ float sred[ET];
    __shared__ float w1cS[HID];

    const int tid = threadIdx.x;
    const int l = tid & 63, w = tid >> 6;
    const int l16 = l & 15, quad = l >> 4;
    const int c0 = (2*w)*16 + l16, c1c = (2*w+1)*16 + l16;
    const int half = tid >> 7, ch = tid & 127;

    if (tid < HID) w1cS[tid] = w1c[tid];

    s8 w2f[8], c1f[8];
    #pragma unroll
    for (int kc = 0; kc < 4; ++kc) {
        w2f[kc]     = *(const s8*)(w2p + (((size_t)(2*w)*4 + kc)*64 + l)*8);
        w2f[4 + kc] = *(const s8*)(w2p + (((size_t)(2*w+1)*4 + kc)*64 + l)*8);
        c1f[kc]     = *(const s8*)(c1p + (((size_t)(2*w)*4 + kc)*64 + l)*8);
        c1f[4 + kc] = *(const s8*)(c1p + (((size_t)(2*w+1)*4 + kc)*64 + l)*8);
    }
    const float bia2_0 = b2[c0],  bia2_1 = b2[c1c];
    const float biac_0 = cb1[c0], biac_1 = cb1[c1c];
    const float cw0    = cw2[c0], cw1v   = cw2[c1c];

    // prefetch state: this lane's edge = tile*64 + w*16 + l16, channels
    // kc*32 + quad*8 + j  (exactly the 16x16x32 A-fragment mapping)
    int pr_r = 0, pr_c = 0;
    float prel0 = 0.f, prel1 = 0.f, prel2 = 0.f, pd2 = 0.f;
    s8 ga[4], gb[4];

    auto PRE = [&](int T) {
        long ge = (long)T * ET + w*16 + l16;
        pr_r = rS[ge]; pr_c = cS[ge];
        float rx = pos[pr_r*3+0] - pos[pr_c*3+0];
        float ry = pos[pr_r*3+1] - pos[pr_c*3+1];
        float rz = pos[pr_r*3+2] - pos[pr_c*3+2];
        prel0 = rx; prel1 = ry; prel2 = rz;
        pd2 = fminf(fmaxf(rx*rx + ry*ry + rz*rz, 1e-6f), 1e6f);
        const short* pa = H1 + (long)pr_r*256 + quad*8;
        const short* pb = H1 + (long)pr_c*256 + 128 + quad*8;
        #pragma unroll
        for (int kc = 0; kc < 4; ++kc) {
            ga[kc] = *(const s8*)(pa + kc*32);
            gb[kc] = *(const s8*)(pb + kc*32);
        }
    };

    int t = blockIdx.x;
    if (t < NTILE) PRE(t);

    while (t < NTILE) {
        __syncthreads();                 // (A) previous tile's LDS fully read
        if (quad == 0) {
            int e = w*16 + l16;
            rIs[e] = pr_r;
            relS[e][0] = prel0; relS[e][1] = prel1; relS[e][2] = prel2;
        }
        if (tid < ET) sred[tid] = 0.f;
        // build t1 A-channels from prefetched regs (stage 1 elementwise)
        {
            float d2 = pd2;
            int row = w*16 + l16;
            #pragma unroll
            for (int kc = 0; kc < 4; ++kc) {
                f4 wva = *(const f4*)&w1cS[kc*32 + quad*8];
                f4 wvb = *(const f4*)&w1cS[kc*32 + quad*8 + 4];
                s8 o;
                #pragma unroll
                for (int j = 0; j < 8; ++j) {
                    float wv = (j < 4) ? wva[j & 3] : wvb[j & 3];
                    float v = b2f(ga[kc][j]) + b2f(gb[kc][j]) + d2*wv;
                    o[j] = f2b(siluf(v));
                }
                *(s8*)&t1[row][kc*32 + quad*8] = o;
            }
        }
        __syncthreads();                 // (B) t1 + meta ready

        int tn = t + PBLK;
        if (tn < NTILE) PRE(tn);         // loads drain during both MFMA stages

        // ---- stage 2: m = silu(t1 @ w2 + b2) -> mm bf16
        {
            f4 acc[4][2];
            #pragma unroll
            for (int mt = 0; mt < 4; ++mt) { acc[mt][0] = (f4)0.f; acc[mt][1] = (f4)0.f; }
            #pragma unroll
            for (int kc = 0; kc < 4; ++kc) {
                #pragma unroll
                for (int mt = 0; mt < 4; ++mt) {
                    s8 a = *(const s8*)&t1[mt*16 + l16][kc*32 + quad*8];
                    acc[mt][0] = __builtin_amdgcn_mfma_f32_16x16x32_bf16(a, w2f[kc],     acc[mt][0], 0, 0, 0);
                    acc[mt][1] = __builtin_amdgcn_mfma_f32_16x16x32_bf16(a, w2f[4 + kc], acc[mt][1], 0, 0, 0);
                }
            }
            #pragma unroll
            for (int mt = 0; mt < 4; ++mt) {
                #pragma unroll
                for (int i = 0; i < 4; ++i) {
                    int row = mt*16 + quad*4 + i;
                    mm[row][c0]  = f2b(siluf(acc[mt][0][i] + bia2_0));
                    mm[row][c1c] = f2b(siluf(acc[mt][1][i] + bia2_1));
                }
            }
        }
        __syncthreads();                 // (C) mm ready

        // ---- stage 3: c1 = silu(mm @ cw1 + cb1); dot cw2 -> sred
        {
            f4 acc[4][2];
            #pragma unroll
            for (int mt = 0; mt < 4; ++mt) { acc[mt][0] = (f4)0.f; acc[mt][1] = (f4)0.f; }
            #pragma unroll
            for (int kc = 0; kc < 4; ++kc) {
                #pragma unroll
                for (int mt = 0; mt < 4; ++mt) {
                    s8 a = *(const s8*)&mm[mt*16 + l16][kc*32 + quad*8];
                    acc[mt][0] = __builtin_amdgcn_mfma_f32_16x16x32_bf16(a, c1f[kc],     acc[mt][0], 0, 0, 0);
                    acc[mt][1] = __builtin_amdgcn_mfma_f32_16x16x32_bf16(a, c1f[4 + kc], acc[mt][1], 0, 0, 0);
                }
            }
            #pragma unroll
            for (int mt = 0; mt < 4; ++mt) {
                #pragma unroll
                for (int i = 0; i < 4; ++i) {
                    float p = siluf(acc[mt][0][i] + biac_0) * cw0
                            + siluf(acc[mt][1][i] + biac_1) * cw1v;
                    p += __shfl_xor(p, 1);
                    p += __shfl_xor(p, 2);
                    p += __shfl_xor(p, 4);
                    p += __shfl_xor(p, 8);
                    if (l16 == 0) {
                        int row = mt*16 + quad*4 + i;
                        atomicAdd(&sred[row], p);
                    }
                }
            }
        }

        // ---- segmented agg reduction over sorted rows (reads mm bf16)
        {
            int e0 = half * 32;
            int cur = rIs[e0];
            float a = 0.f;
            #pragma unroll
            for (int e = e0; e < e0 + 32; ++e) {
                int r = rIs[e];
                if (r != cur) {
                    atomicAdd(&agg[(long)cur*HID + ch], a);
                    a = 0.f; cur = r;
                }
                a += b2f(mm[e][ch]);
            }
            atomicAdd(&agg[(long)cur*HID + ch], a);
        }
        __syncthreads();                 // (D) sred complete

        if (tid < ET) {
            float cwv = fminf(fmaxf(sred[tid], -1.f), 1.f);
            int r = rIs[tid];
            atomicAdd(&upd[r*3+0], cwv*relS[tid][0]);
            atomicAdd(&upd[r*3+1], cwv*relS[tid][1]);
            atomicAdd(&upd[r*3+2], cwv*relS[tid][2]);
        }
        t = tn;
    }
}

// ---------------------------------------------------------------------------
// MFMA node kernel: 64 nodes/block; x=[h|agg] bf16; LN in f32; writes hb.
__global__ __launch_bounds__(256) void k_node_mfma(
    short* __restrict__ hb, const float* __restrict__ agg,
    const short* __restrict__ w1p, const float* __restrict__ b1n,
    const short* __restrict__ w2p, const float* __restrict__ b2n,
    const float* __restrict__ lg, const float* __restrict__ lb,
    float* __restrict__ pos, const float* __restrict__ upd,
    const int* __restrict__ rowStart)
{
    __shared__ short x[64][264];
    __shared__ short t1[64][144];
    __shared__ float mus[64], rstds[64];
    float (*hn)[132] = (float (*)[132])&x[0][0];

    const int tid = threadIdx.x;
    const int n0 = blockIdx.x * 64;

    #pragma unroll
    for (int it = 0; it < 4; ++it) {
        int idx = it*256 + tid;
        int e = idx >> 4, q = idx & 15;
        *(int4*)&x[e][q*8] = *(const int4*)(hb + (long)(n0+e)*HID + q*8);
    }
    #pragma unroll
    for (int it = 0; it < 8; ++it) {
        int idx = it*256 + tid;
        int e = idx >> 5, q = idx & 31;
        float4 v = *(const float4*)(agg + (long)(n0+e)*HID + q*4);
        short4 sv;
        sv.x = f2b(v.x); sv.y = f2b(v.y); sv.z = f2b(v.z); sv.w = f2b(v.w);
        *(short4*)&x[e][128 + q*4] = sv;
    }
    __syncthreads();

    const int l = tid & 63, w = tid >> 6;
    const int l16 = l & 15, quad = l >> 4;
    const int nt0 = 2*w, nt1 = 2*w + 1;
    const int c0 = nt0*16 + l16, c1c = nt1*16 + l16;

    {
        f4 acc[4][2];
        #pragma unroll
        for (int mt = 0; mt < 4; ++mt) { acc[mt][0] = (f4)0.f; acc[mt][1] = (f4)0.f; }
        #pragma unroll
        for (int kc = 0; kc < 8; ++kc) {
            s8 b0  = *(const s8*)(w1p + (((size_t)nt0*8 + kc)*64 + l)*8);
            s8 b1f = *(const s8*)(w1p + (((size_t)nt1*8 + kc)*64 + l)*8);
            #pragma unroll
            for (int mt = 0; mt < 4; ++mt) {
                s8 a = *(const s8*)&x[mt*16 + l16][kc*32 + quad*8];
                acc[mt][0] = __builtin_amdgcn_mfma_f32_16x16x32_bf16(a, b0,  acc[mt][0], 0, 0, 0);
                acc[mt][1] = __builtin_amdgcn_mfma_f32_16x16x32_bf16(a, b1f, acc[mt][1], 0, 0, 0);
            }
        }
        float bia0 = b1n[c0], bia1 = b1n[c1c];
        #pragma unroll
        for (int mt = 0; mt < 4; ++mt) {
            #pragma unroll
            for (int i = 0; i < 4; ++i) {
                int row = mt*16 + quad*4 + i;
                t1[row][c0]  = f2b(siluf(acc[mt][0][i] + bia0));
                t1[row][c1c] = f2b(siluf(acc[mt][1][i] + bia1));
            }
        }
    }
    __syncthreads();

    {
        f4 acc[4][2];
        #pragma unroll
        for (int mt = 0; mt < 4; ++mt) { acc[mt][0] = (f4)0.f; acc[mt][1] = (f4)0.f; }
        #pragma unroll
        for (int kc = 0; kc < 4; ++kc) {
            s8 b0  = *(const s8*)(w2p + (((size_t)nt0*4 + kc)*64 + l)*8);
            s8 b1f = *(const s8*)(w2p + (((size_t)nt1*4 + kc)*64 + l)*8);
            #pragma unroll
            for (int mt = 0; mt < 4; ++mt) {
                s8 a = *(const s8*)&t1[mt*16 + l16][kc*32 + quad*8];
                acc[mt][0] = __builtin_amdgcn_mfma_f32_16x16x32_bf16(a, b0,  acc[mt][0], 0, 0, 0);
                acc[mt][1] = __builtin_amdgcn_mfma_f32_16x16x32_bf16(a, b1f, acc[mt][1], 0, 0, 0);
            }
        }
        float bia0 = b2n[c0], bia1 = b2n[c1c];
        __syncthreads();
        #pragma unroll
        for (int mt = 0; mt < 4; ++mt) {
            #pragma unroll
            for (int i = 0; i < 4; ++i) {
                int row = mt*16 + quad*4 + i;
                hn[row][c0]  = acc[mt][0][i] + bia0;
                hn[row][c1c] = acc[mt][1][i] + bia1;
            }
        }
    }
    __syncthreads();

    {
        int r = tid >> 2, part = tid & 3;
        float s = 0.f, q = 0.f;
        #pragma unroll
        for (int j = 0; j < 32; ++j) {
            float v = hn[r][part + 4*j];
            s += v; q += v*v;
        }
        s += __shfl_xor(s, 1); q += __shfl_xor(q, 1);
        s += __shfl_xor(s, 2); q += __shfl_xor(q, 2);
        if (part == 0) {
            float mu = s * (1.0f/HID);
            float var = q * (1.0f/HID) - mu*mu;
            mus[r] = mu;
            rstds[r] = rsqrtf(var + 1e-5f);
        }
    }
    __syncthreads();

    #pragma unroll
    for (int it = 0; it < 32; ++it) {
        int idx = it*256 + tid;
        int r = idx >> 7, c = idx & 127;
        float v = (hn[r][c] - mus[r]) * rstds[r] * lg[c] + lb[c];
        hb[(long)(n0 + r)*HID + c] = f2b(v);
    }
    if (tid < 192) {
        int i = tid / 3, d = tid - i*3;
        int n = n0 + i;
        float dg = (float)(rowStart[n+1] - rowStart[n]);
        pos[n*3+d] += upd[n*3+d] / (dg + 1e-6f);
    }
}

// ---------------------------------------------------------------------------
__global__ void k_head(const short* __restrict__ hb, const float* __restrict__ pos,
                       const float* __restrict__ w1, const float* __restrict__ b1,
                       const float* __restrict__ w2, const float* __restrict__ b2,
                       void* __restrict__ out, const int* __restrict__ flags)
{
    __shared__ float hs[4][HID];
    __shared__ float t[4][64];
    const int tid = threadIdx.x;
    const int n0 = blockIdx.x * 4;
    for (int i = tid; i < 4*HID; i += 256)
        hs[i >> 7][i & 127] = b2f(hb[(long)n0*HID + i]);
    __syncthreads();
    const int s = tid >> 6, c = tid & 63;
    float acc = b1[c];
    for (int k4 = 0; k4 < 32; ++k4) {
        int k = k4*4;
        float wa = w1[(k+0)*64 + c];
        float wb = w1[(k+1)*64 + c];
        float wc = w1[(k+2)*64 + c];
        float wd = w1[(k+3)*64 + c];
        float4 v = *(const float4*)&hs[s][k];
        acc += v.x*wa + v.y*wb + v.z*wc + v.w*wd;
    }
    t[s][c] = siluf(acc);
    __syncthreads();
    if (c < 3) {
        float a2 = b2[c];
        #pragma unroll
        for (int k = 0; k < 64; ++k) a2 += t[s][k] * w2[k*3 + c];
        int n = n0 + s;
        float v = pos[n*3+c] + a2;
        if (flags[0]) ((__hip_bfloat16*)out)[n*3+c] = __float2bfloat16(v);
        else          ((float*)out)[n*3+c] = v;
    }
}

// ---------------------------------------------------------------------------
extern "C" void kernel_launch(void* const* d_in, const int* in_sizes, int n_in,
                              void* d_out, int out_size, void* d_ws, size_t ws_size,
                              hipStream_t stream)
{
    (void)in_sizes; (void)n_in; (void)out_size; (void)ws_size;

    int* flags = (int*)d_ws;
    float* base = (float*)d_ws;
    size_t off = 64;
    auto alloc = [&](size_t n) { float* p = base + off; off += (n + 63) & ~63ull; return p; };

    static const int aidx[24] = {0,1,3,4,5,6,7,8,9,10,11,12,13,14,15,16,17,18,19,20,21,22,23,24};
    static const int alen[24] = {
        BB*LAT, NN*AF, NA*3, LAT*HID, HID, AF*HID, HID,
        NL*257*HID, NL*HID, NL*HID*HID, NL*HID,
        NL*256*HID, NL*HID, NL*HID*HID, NL*HID,
        NL*HID*HID, NL*HID, NL*HID, NL*HID, NL*HID,
        HID*64, 64, 64*3, 3
    };
    CvtDesc cd;
    float* fp[24];
    for (int a = 0; a < 24; ++a) {
        fp[a] = alloc((size_t)alen[a]);
        cd.src[a] = d_in[aidx[a]];
        cd.dst[a] = fp[a];
        cd.len[a] = alen[a];
    }
    float* agg = alloc((size_t)NN*HID);
    float* hz  = alloc((size_t)BB*HID);
    float* pos = alloc((size_t)NN*3);
    float* upd = alloc((size_t)NN*3);
    short* hb  = (short*)alloc((size_t)NN*HID/2);
    short* H1  = (short*)alloc((size_t)NN*256/2);
    short* wcatp = (short*)alloc((size_t)NL*32768/2);
    short* w2p = (short*)alloc((size_t)NL*16384/2);
    short* c1p = (short*)alloc((size_t)NL*16384/2);
    short* nw1p = (short*)alloc((size_t)NL*32768/2);
    short* nw2p = (short*)alloc((size_t)NL*16384/2);
    int* cnt      = (int*)alloc((size_t)NN);
    int* rowStart = (int*)alloc((size_t)NN + 1);
    int* cursor   = (int*)alloc((size_t)NN);
    int* rS       = (int*)alloc((size_t)NE);
    int* cS       = (int*)alloc((size_t)NE);
    const int* eidx = (const int*)d_in[2];

    k_detect<<<1, 256, 0, stream>>>((const unsigned short*)d_in[0],
                                    (const unsigned int*)d_in[2], flags);
    k_convert<<<dim3((NN*AF + 255)/256, 24), 256, 0, stream>>>(cd, flags);

    PackJobs pj;
    for (int l = 0; l < NL; ++l) {
        int b5 = l*5;
        pj.src[b5+0] = fp[7]  + (size_t)l*257*HID; pj.dst[b5+0] = wcatp + (size_t)l*32768; pj.K[b5+0] = 256; pj.mode[b5+0] = 1;
        pj.src[b5+1] = fp[9]  + (size_t)l*HID*HID; pj.dst[b5+1] = w2p   + (size_t)l*16384; pj.K[b5+1] = 128; pj.mode[b5+1] = 0;
        pj.src[b5+2] = fp[15] + (size_t)l*HID*HID; pj.dst[b5+2] = c1p   + (size_t)l*16384; pj.K[b5+2] = 128; pj.mode[b5+2] = 0;
        pj.src[b5+3] = fp[11] + (size_t)l*256*HID; pj.dst[b5+3] = nw1p  + (size_t)l*32768; pj.K[b5+3] = 256; pj.mode[b5+3] = 0;
        pj.src[b5+4] = fp[13] + (size_t)l*HID*HID; pj.dst[b5+4] = nw2p  + (size_t)l*16384; pj.K[b5+4] = 128; pj.mode[b5+4] = 0;
    }
    k_packall<<<dim3(128, 10), 256, 0, stream>>>(pj);

    // counting sort edges by row
    k_zero_cnt<<<(NN + 255)/256, 256, 0, stream>>>(cnt);
    k_hist<<<(NE + 255)/256, 256, 0, stream>>>(eidx, flags, cnt);
    k_scan<<<1, 1024, 0, stream>>>(cnt, rowStart, cursor);
    k_scatter<<<(NE + 255)/256, 256, 0, stream>>>(eidx, flags, cursor, rS, cS);

    k_hz<<<BB, HID, 0, stream>>>(fp[0], fp[3], fp[4], hz);
    k_init2<<<NN, HID, 0, stream>>>(hz, fp[1], fp[5], fp[6], fp[2], pos, hb);

    for (int l = 0; l < NL; ++l) {
        k_zero<<<(NN*HID + 255)/256, 256, 0, stream>>>(agg, upd);
        k_pre<<<NN/64, 256, 0, stream>>>(hb, wcatp + (size_t)l*32768,
                                         fp[8] + (size_t)l*HID, H1);
        k_edge3<<<PBLK, 256, 0, stream>>>(H1, pos, rS, cS,
            fp[7] + (size_t)l*257*HID + 256*HID,       // w1c (d2 row, f32)
            w2p + (size_t)l*16384, fp[10] + (size_t)l*HID,
            c1p + (size_t)l*16384, fp[16] + (size_t)l*HID,
            fp[17] + (size_t)l*HID,
            agg, upd);
        k_node_mfma<<<NN/64, 256, 0, stream>>>(hb, agg,
            nw1p + (size_t)l*32768, fp[12] + (size_t)l*HID,
            nw2p + (size_t)l*16384, fp[14] + (size_t)l*HID,
            fp[18] + (size_t)l*HID, fp[19] + (size_t)l*HID,
            pos, upd, rowStart);
    }
    k_head<<<NN/4, 256, 0, stream>>>(hb, pos, fp[20], fp[21], fp[22], fp[23],
                                     d_out, flags);
}

// Round 7
// 728.506 us; speedup vs baseline: 1.0184x; 1.0184x over previous
//
#include <hip/hip_runtime.h>
#include <hip/hip_bf16.h>

#define BB 512
#define NA 58
#define LAT 64
#define HID 128
#define AF 10
#define NL 2
#define NN (BB*NA)      // 29696
#define NE (NN*16)      // 475136
#define ET 64           // edges per tile
#define NTILE (NE/ET)   // 7424
#define PBLK 1024       // persistent blocks (4 per CU)

typedef __attribute__((ext_vector_type(8))) short s8;
typedef __attribute__((ext_vector_type(4))) float f4;

struct CvtDesc {
    const void* src[24];
    float*      dst[24];
    int         len[24];
};

struct PackJobs {
    const float* src[10];
    short*       dst[10];
    int          K[10];
    int          mode[10];
};

__device__ __forceinline__ float siluf(float x) {
    return x * __builtin_amdgcn_rcpf(1.0f + __expf(-x));
}

__device__ __forceinline__ short f2b(float x) {
    __hip_bfloat16 b = __float2bfloat16(x);
    return *(short*)&b;
}

__device__ __forceinline__ float b2f(short s) {
    return __uint_as_float(((unsigned int)(unsigned short)s) << 16);
}

// ---------------------------------------------------------------------------
__global__ void k_detect(const unsigned short* __restrict__ z16,
                         const unsigned int* __restrict__ e32,
                         int* __restrict__ flags) {
    __shared__ int sbf, si64;
    if (threadIdx.x == 0) { sbf = 0; si64 = 0; }
    __syncthreads();
    int c1 = 0, c2 = 0;
    for (int i = threadIdx.x; i < 1024; i += 256) {
        unsigned short v = z16[2*i];
        int e = (v >> 7) & 0xFF;
        if (e >= 100 && e <= 140) c1++;
        if (e32[2*i + 1] == 0u) c2++;
    }
    atomicAdd(&sbf, c1);
    atomicAdd(&si64, c2);
    __syncthreads();
    if (threadIdx.x == 0) {
        flags[0] = (sbf  > 600) ? 1 : 0;
        flags[1] = (si64 > 600) ? 1 : 0;
    }
}

__global__ void k_convert(CvtDesc d, const int* __restrict__ flags) {
    int a = blockIdx.y;
    int i = blockIdx.x * blockDim.x + threadIdx.x;
    int n = d.len[a];
    if (i >= n) return;
    if (flags[0]) {
        d.dst[a][i] = __bfloat162float(((const __hip_bfloat16*)d.src[a])[i]);
    } else {
        d.dst[a][i] = ((const float*)d.src[a])[i];
    }
}

__global__ void k_packall(PackJobs pj) {
    int j = blockIdx.y;
    int idx = blockIdx.x * 256 + threadIdx.x;
    const float* w = pj.src[j];
    short* o = pj.dst[j];
    if (pj.mode[j] == 0) {
        int K = pj.K[j];
        if (idx >= 128*K) return;
        int jj = idx & 7;
        int l  = (idx >> 3) & 63;
        int rest = idx >> 9;
        int KC = K >> 5;
        int kc = rest % KC;
        int nt = rest / KC;
        int n = nt*16 + (l & 15);
        int k = kc*32 + (l >> 4)*8 + jj;
        o[idx] = f2b(w[k*128 + n]);
    } else {
        if (idx >= 32768) return;
        int jj = idx & 7;
        int l  = (idx >> 3) & 63;
        int rest = idx >> 9;
        int kc = rest & 3;
        int nt = rest >> 2;
        int n = nt*16 + (l & 15);
        int k = kc*32 + (l >> 4)*8 + jj;
        float v = (n < 128) ? w[k*128 + n] : w[(128 + k)*128 + (n - 128)];
        o[idx] = f2b(v);
    }
}

// ---------------------------------------------------------------------------
// counting sort of edges by row
__global__ void k_zero_cnt(int* __restrict__ cnt) {
    int i = blockIdx.x * 256 + threadIdx.x;
    if (i < NN) cnt[i] = 0;
}

__global__ void k_hist(const int* __restrict__ eidx, const int* __restrict__ flags,
                       int* __restrict__ cnt) {
    int e = blockIdx.x * 256 + threadIdx.x;
    if (e >= NE) return;
    int is64 = flags[1];
    int r = eidx[is64 ? 2*(long)e : (long)e];
    atomicAdd(&cnt[r], 1);
}

__global__ __launch_bounds__(1024) void k_scan(const int* __restrict__ cnt,
                                               int* __restrict__ rowStart,
                                               int* __restrict__ cursor) {
    __shared__ int part[1024];
    int t = threadIdx.x;
    int base = t * 29;                    // NN == 1024*29
    int loc[29];
    int s = 0;
    #pragma unroll
    for (int i = 0; i < 29; ++i) { loc[i] = s; s += cnt[base + i]; }
    part[t] = s;
    __syncthreads();
    for (int d = 1; d < 1024; d <<= 1) {
        int v = (t >= d) ? part[t - d] : 0;
        __syncthreads();
        part[t] += v;
        __syncthreads();
    }
    int pre = (t == 0) ? 0 : part[t - 1];
    #pragma unroll
    for (int i = 0; i < 29; ++i) {
        int v = pre + loc[i];
        rowStart[base + i] = v;
        cursor[base + i] = v;
    }
    if (t == 1023) rowStart[NN] = pre + s;
}

__global__ void k_scatter(const int* __restrict__ eidx, const int* __restrict__ flags,
                          int* __restrict__ cursor,
                          int* __restrict__ rS, int* __restrict__ cS) {
    int e = blockIdx.x * 256 + threadIdx.x;
    if (e >= NE) return;
    int is64 = flags[1];
    long ge = e, gc = (long)e + NE;
    int r = eidx[is64 ? 2*ge : ge];
    int c = eidx[is64 ? 2*gc : gc];
    int p = atomicAdd(&cursor[r], 1);
    rS[p] = r; cS[p] = c;
}

// ---------------------------------------------------------------------------
__global__ void k_hz(const float* __restrict__ z, const float* __restrict__ lw,
                     const float* __restrict__ lb, float* __restrict__ hz) {
    __shared__ float zs[LAT];
    int b = blockIdx.x;
    int c = threadIdx.x;
    if (c < LAT) zs[c] = z[b*LAT + c];
    __syncthreads();
    float acc = lb[c];
    #pragma unroll
    for (int k = 0; k < LAT; ++k) acc += zs[k] * lw[k*HID + c];
    hz[b*HID + c] = acc;
}

__global__ void k_init2(const float* __restrict__ hz, const float* __restrict__ at,
                        const float* __restrict__ aw, const float* __restrict__ ab,
                        const float* __restrict__ ic,
                        float* __restrict__ pos, short* __restrict__ hb) {
    __shared__ float ats[AF];
    int n = blockIdx.x;
    int c = threadIdx.x;
    int b = n / NA;
    if (c < AF) ats[c] = at[n*AF + c];
    __syncthreads();
    float acc = hz[b*HID + c] + ab[c];
    #pragma unroll
    for (int f = 0; f < AF; ++f) acc += ats[f] * aw[f*HID + c];
    hb[(long)n*HID + c] = f2b(acc);
    if (c < 3) {
        int a = n % NA;
        pos[n*3 + c] = ic[a*3 + c];
    }
}

// per-layer: edge geometry planes + zero agg/upd (fused)
__global__ void k_gz(const int* __restrict__ rS, const int* __restrict__ cS,
                     const float* __restrict__ pos,
                     float* __restrict__ relX, float* __restrict__ relY,
                     float* __restrict__ relZ, float* __restrict__ d2S,
                     float* __restrict__ agg, float* __restrict__ upd) {
    int i = blockIdx.x * 256 + threadIdx.x;      // grid covers NE exactly
    if (i < NE) {
        int r = rS[i], c = cS[i];
        float rx = pos[r*3+0] - pos[c*3+0];
        float ry = pos[r*3+1] - pos[c*3+1];
        float rz = pos[r*3+2] - pos[c*3+2];
        relX[i] = rx; relY[i] = ry; relZ[i] = rz;
        d2S[i] = fminf(fmaxf(rx*rx + ry*ry + rz*rz, 1e-6f), 1e6f);
    }
    f4* a4 = (f4*)agg;
    for (long j = i; j < (long)NN*HID/4; j += (long)gridDim.x*256) a4[j] = (f4)0.f;
    if (i < NN*3) upd[i] = 0.f;
}

// ---------------------------------------------------------------------------
// H1 = hb @ [w1a|w1b] (+ b1 on a-half) -> [NN][256] bf16.
__global__ __launch_bounds__(256) void k_pre(
    const short* __restrict__ hb, const short* __restrict__ wcat,
    const float* __restrict__ b1, short* __restrict__ H1)
{
    __shared__ short x[64][136];
    const int tid = threadIdx.x;
    const int n0 = blockIdx.x * 64;

    #pragma unroll
    for (int it = 0; it < 4; ++it) {
        int idx = it*256 + tid;
        int e = idx >> 4, q = idx & 15;
        *(int4*)&x[e][q*8] = *(const int4*)(hb + (long)(n0+e)*HID + q*8);
    }
    __syncthreads();

    const int l = tid & 63, w = tid >> 6;
    const int l16 = l & 15, quad = l >> 4;

    f4 acc[4][4];
    #pragma unroll
    for (int mt = 0; mt < 4; ++mt)
        #pragma unroll
        for (int nt4 = 0; nt4 < 4; ++nt4) acc[mt][nt4] = (f4)0.f;

    #pragma unroll
    for (int kc = 0; kc < 4; ++kc) {
        s8 a[4];
        #pragma unroll
        for (int mt = 0; mt < 4; ++mt)
            a[mt] = *(const s8*)&x[mt*16 + l16][kc*32 + quad*8];
        #pragma unroll
        for (int nt4 = 0; nt4 < 4; ++nt4) {
            int nt = w*4 + nt4;
            s8 b = *(const s8*)(wcat + (((size_t)nt*4 + kc)*64 + l)*8);
            #pragma unroll
            for (int mt = 0; mt < 4; ++mt)
                acc[mt][nt4] = __builtin_amdgcn_mfma_f32_16x16x32_bf16(a[mt], b, acc[mt][nt4], 0, 0, 0);
        }
    }
    #pragma unroll
    for (int nt4 = 0; nt4 < 4; ++nt4) {
        int col = (w*4 + nt4)*16 + l16;
        float bias = (col < 128) ? b1[col] : 0.f;
        #pragma unroll
        for (int mt = 0; mt < 4; ++mt)
            #pragma unroll
            for (int i = 0; i < 4; ++i) {
                int row = mt*16 + quad*4 + i;
                H1[(long)(n0 + row)*256 + col] = f2b(acc[mt][nt4][i] + bias);
            }
    }
}

// ---------------------------------------------------------------------------
// Edge kernel v4: cooperative coalesced prefetch (256B/16 lanes), geometry
// precomputed, 4 barriers, 4 blocks/CU.
__global__ __launch_bounds__(256, 4) void k_edge4(
    const short* __restrict__ H1,
    const int* __restrict__ rS, const int* __restrict__ cS,
    const float* __restrict__ relX, const float* __restrict__ relY,
    const float* __restrict__ relZ, const float* __restrict__ d2S,
    const float* __restrict__ w1c,
    const short* __restrict__ w2p, const float* __restrict__ b2,
    const short* __restrict__ c1p, const float* __restrict__ cb1,
    const float* __restrict__ cw2,
    float* __restrict__ agg, float* __restrict__ upd)
{
    __shared__ short t1[ET][136];
    __shared__ short mm[ET][136];
    __shared__ int   rIs[ET];
    __shared__ float sred[ET];

    const int tid = threadIdx.x;
    const int l = tid & 63, w = tid >> 6;
    const int l16 = l & 15, quad = l >> 4;
    const int c0 = (2*w)*16 + l16, c1c = (2*w+1)*16 + l16;
    const int half = tid >> 7, ch = tid & 127;
    const int q = tid & 15;          // this thread's channel chunk (fixed!)
    const int esub = tid >> 4;       // edge subgroup 0..15

    // per-thread w1c channels in registers
    float wv[8];
    #pragma unroll
    for (int j = 0; j < 8; ++j) wv[j] = w1c[q*8 + j];

    s8 w2f[8], c1f[8];
    #pragma unroll
    for (int kc = 0; kc < 4; ++kc) {
        w2f[kc]     = *(const s8*)(w2p + (((size_t)(2*w)*4 + kc)*64 + l)*8);
        w2f[4 + kc] = *(const s8*)(w2p + (((size_t)(2*w+1)*4 + kc)*64 + l)*8);
        c1f[kc]     = *(const s8*)(c1p + (((size_t)(2*w)*4 + kc)*64 + l)*8);
        c1f[4 + kc] = *(const s8*)(c1p + (((size_t)(2*w+1)*4 + kc)*64 + l)*8);
    }
    const float bia2_0 = b2[c0],  bia2_1 = b2[c1c];
    const float biac_0 = cb1[c0], biac_1 = cb1[c1c];
    const float cw0    = cw2[c0], cw1v   = cw2[c1c];

    // prefetch state (cooperative: thread owns chunk q of edges esub+16*it)
    s8 va[4], vb[4];
    float d2v[4];
    int pr_r = 0;

    auto PRE = [&](int T) {
        long eb = (long)T * ET;
        #pragma unroll
        for (int it = 0; it < 4; ++it) {
            int e = esub + 16*it;
            int ri = rS[eb + e];
            int ci = cS[eb + e];
            d2v[it] = d2S[eb + e];
            va[it] = *(const s8*)(H1 + (long)ri*256 + q*8);
            vb[it] = *(const s8*)(H1 + (long)ci*256 + 128 + q*8);
        }
        pr_r = rS[eb + (tid & 63)];
    };

    int t = blockIdx.x;
    if (t < NTILE) PRE(t);

    while (t < NTILE) {
        __syncthreads();                 // (A) previous tile fully consumed
        if (tid < ET) { rIs[tid] = pr_r; sred[tid] = 0.f; }
        // build t1 from prefetched regs
        #pragma unroll
        for (int it = 0; it < 4; ++it) {
            int e = esub + 16*it;
            float d2 = d2v[it];
            s8 o;
            #pragma unroll
            for (int j = 0; j < 8; ++j) {
                float v = b2f(va[it][j]) + b2f(vb[it][j]) + d2*wv[j];
                o[j] = f2b(siluf(v));
            }
            *(s8*)&t1[e][q*8] = o;
        }
        __syncthreads();                 // (B) t1 + meta ready

        int tn = t + PBLK;
        if (tn < NTILE) PRE(tn);         // drains during both MFMA stages

        // ---- stage 2: m = silu(t1 @ w2 + b2) -> mm bf16
        {
            f4 acc[4][2];
            #pragma unroll
            for (int mt = 0; mt < 4; ++mt) { acc[mt][0] = (f4)0.f; acc[mt][1] = (f4)0.f; }
            #pragma unroll
            for (int kc = 0; kc < 4; ++kc) {
                #pragma unroll
                for (int mt = 0; mt < 4; ++mt) {
                    s8 a = *(const s8*)&t1[mt*16 + l16][kc*32 + quad*8];
                    acc[mt][0] = __builtin_amdgcn_mfma_f32_16x16x32_bf16(a, w2f[kc],     acc[mt][0], 0, 0, 0);
                    acc[mt][1] = __builtin_amdgcn_mfma_f32_16x16x32_bf16(a, w2f[4 + kc], acc[mt][1], 0, 0, 0);
                }
            }
            #pragma unroll
            for (int mt = 0; mt < 4; ++mt) {
                #pragma unroll
                for (int i = 0; i < 4; ++i) {
                    int row = mt*16 + quad*4 + i;
                    mm[row][c0]  = f2b(siluf(acc[mt][0][i] + bia2_0));
                    mm[row][c1c] = f2b(siluf(acc[mt][1][i] + bia2_1));
                }
            }
        }
        __syncthreads();                 // (C) mm ready

        // ---- stage 3: c1 = silu(mm @ cw1 + cb1); dot cw2 -> sred
        {
            f4 acc[4][2];
            #pragma unroll
            for (int mt = 0; mt < 4; ++mt) { acc[mt][0] = (f4)0.f; acc[mt][1] = (f4)0.f; }
            #pragma unroll
            for (int kc = 0; kc < 4; ++kc) {
                #pragma unroll
                for (int mt = 0; mt < 4; ++mt) {
                    s8 a = *(const s8*)&mm[mt*16 + l16][kc*32 + quad*8];
                    acc[mt][0] = __builtin_amdgcn_mfma_f32_16x16x32_bf16(a, c1f[kc],     acc[mt][0], 0, 0, 0);
                    acc[mt][1] = __builtin_amdgcn_mfma_f32_16x16x32_bf16(a, c1f[4 + kc], acc[mt][1], 0, 0, 0);
                }
            }
            #pragma unroll
            for (int mt = 0; mt < 4; ++mt) {
                #pragma unroll
                for (int i = 0; i < 4; ++i) {
                    float p = siluf(acc[mt][0][i] + biac_0) * cw0
                            + siluf(acc[mt][1][i] + biac_1) * cw1v;
                    p += __shfl_xor(p, 1);
                    p += __shfl_xor(p, 2);
                    p += __shfl_xor(p, 4);
                    p += __shfl_xor(p, 8);
                    if (l16 == 0) {
                        int row = mt*16 + quad*4 + i;
                        atomicAdd(&sred[row], p);
                    }
                }
            }
        }

        // ---- segmented agg reduction over sorted rows (reads mm bf16)
        {
            int e0 = half * 32;
            int cur = rIs[e0];
            float a = 0.f;
            #pragma unroll
            for (int e = e0; e < e0 + 32; ++e) {
                int r = rIs[e];
                if (r != cur) {
                    atomicAdd(&agg[(long)cur*HID + ch], a);
                    a = 0.f; cur = r;
                }
                a += b2f(mm[e][ch]);
            }
            atomicAdd(&agg[(long)cur*HID + ch], a);
        }
        __syncthreads();                 // (D) sred complete

        if (tid < ET) {
            long ge = (long)t*ET + tid;
            float cwv = fminf(fmaxf(sred[tid], -1.f), 1.f);
            int r = rIs[tid];
            atomicAdd(&upd[r*3+0], cwv*relX[ge]);
            atomicAdd(&upd[r*3+1], cwv*relY[ge]);
            atomicAdd(&upd[r*3+2], cwv*relZ[ge]);
        }
        t = tn;
    }
}

// ---------------------------------------------------------------------------
__global__ __launch_bounds__(256) void k_node_mfma(
    short* __restrict__ hb, const float* __restrict__ agg,
    const short* __restrict__ w1p, const float* __restrict__ b1n,
    const short* __restrict__ w2p, const float* __restrict__ b2n,
    const float* __restrict__ lg, const float* __restrict__ lb,
    float* __restrict__ pos, const float* __restrict__ upd,
    const int* __restrict__ rowStart)
{
    __shared__ short x[64][264];
    __shared__ short t1[64][144];
    __shared__ float mus[64], rstds[64];
    float (*hn)[132] = (float (*)[132])&x[0][0];

    const int tid = threadIdx.x;
    const int n0 = blockIdx.x * 64;

    #pragma unroll
    for (int it = 0; it < 4; ++it) {
        int idx = it*256 + tid;
        int e = idx >> 4, q = idx & 15;
        *(int4*)&x[e][q*8] = *(const int4*)(hb + (long)(n0+e)*HID + q*8);
    }
    #pragma unroll
    for (int it = 0; it < 8; ++it) {
        int idx = it*256 + tid;
        int e = idx >> 5, q = idx & 31;
        float4 v = *(const float4*)(agg + (long)(n0+e)*HID + q*4);
        short4 sv;
        sv.x = f2b(v.x); sv.y = f2b(v.y); sv.z = f2b(v.z); sv.w = f2b(v.w);
        *(short4*)&x[e][128 + q*4] = sv;
    }
    __syncthreads();

    const int l = tid & 63, w = tid >> 6;
    const int l16 = l & 15, quad = l >> 4;
    const int nt0 = 2*w, nt1 = 2*w + 1;
    const int c0 = nt0*16 + l16, c1c = nt1*16 + l16;

    {
        f4 acc[4][2];
        #pragma unroll
        for (int mt = 0; mt < 4; ++mt) { acc[mt][0] = (f4)0.f; acc[mt][1] = (f4)0.f; }
        #pragma unroll
        for (int kc = 0; kc < 8; ++kc) {
            s8 b0  = *(const s8*)(w1p + (((size_t)nt0*8 + kc)*64 + l)*8);
            s8 b1f = *(const s8*)(w1p + (((size_t)nt1*8 + kc)*64 + l)*8);
            #pragma unroll
            for (int mt = 0; mt < 4; ++mt) {
                s8 a = *(const s8*)&x[mt*16 + l16][kc*32 + quad*8];
                acc[mt][0] = __builtin_amdgcn_mfma_f32_16x16x32_bf16(a, b0,  acc[mt][0], 0, 0, 0);
                acc[mt][1] = __builtin_amdgcn_mfma_f32_16x16x32_bf16(a, b1f, acc[mt][1], 0, 0, 0);
            }
        }
        float bia0 = b1n[c0], bia1 = b1n[c1c];
        #pragma unroll
        for (int mt = 0; mt < 4; ++mt) {
            #pragma unroll
            for (int i = 0; i < 4; ++i) {
                int row = mt*16 + quad*4 + i;
                t1[row][c0]  = f2b(siluf(acc[mt][0][i] + bia0));
                t1[row][c1c] = f2b(siluf(acc[mt][1][i] + bia1));
            }
        }
    }
    __syncthreads();

    {
        f4 acc[4][2];
        #pragma unroll
        for (int mt = 0; mt < 4; ++mt) { acc[mt][0] = (f4)0.f; acc[mt][1] = (f4)0.f; }
        #pragma unroll
        for (int kc = 0; kc < 4; ++kc) {
            s8 b0  = *(const s8*)(w2p + (((size_t)nt0*4 + kc)*64 + l)*8);
            s8 b1f = *(const s8*)(w2p + (((size_t)nt1*4 + kc)*64 + l)*8);
            #pragma unroll
            for (int mt = 0; mt < 4; ++mt) {
                s8 a = *(const s8*)&t1[mt*16 + l16][kc*32 + quad*8];
                acc[mt][0] = __builtin_amdgcn_mfma_f32_16x16x32_bf16(a, b0,  acc[mt][0], 0, 0, 0);
                acc[mt][1] = __builtin_amdgcn_mfma_f32_16x16x32_bf16(a, b1f, acc[mt][1], 0, 0, 0);
            }
        }
        float bia0 = b2n[c0], bia1 = b2n[c1c];
        __syncthreads();
        #pragma unroll
        for (int mt = 0; mt < 4; ++mt) {
            #pragma unroll
            for (int i = 0; i < 4; ++i) {
                int row = mt*16 + quad*4 + i;
                hn[row][c0]  = acc[mt][0][i] + bia0;
                hn[row][c1c] = acc[mt][1][i] + bia1;
            }
        }
    }
    __syncthreads();

    {
        int r = tid >> 2, part = tid & 3;
        float s = 0.f, q = 0.f;
        #pragma unroll
        for (int j = 0; j < 32; ++j) {
            float v = hn[r][part + 4*j];
            s += v; q += v*v;
        }
        s += __shfl_xor(s, 1); q += __shfl_xor(q, 1);
        s += __shfl_xor(s, 2); q += __shfl_xor(q, 2);
        if (part == 0) {
            float mu = s * (1.0f/HID);
            float var = q * (1.0f/HID) - mu*mu;
            mus[r] = mu;
            rstds[r] = rsqrtf(var + 1e-5f);
        }
    }
    __syncthreads();

    #pragma unroll
    for (int it = 0; it < 32; ++it) {
        int idx = it*256 + tid;
        int r = idx >> 7, c = idx & 127;
        float v = (hn[r][c] - mus[r]) * rstds[r] * lg[c] + lb[c];
        hb[(long)(n0 + r)*HID + c] = f2b(v);
    }
    if (tid < 192) {
        int i = tid / 3, d = tid - i*3;
        int n = n0 + i;
        float dg = (float)(rowStart[n+1] - rowStart[n]);
        pos[n*3+d] += upd[n*3+d] / (dg + 1e-6f);
    }
}

// ---------------------------------------------------------------------------
__global__ void k_head(const short* __restrict__ hb, const float* __restrict__ pos,
                       const float* __restrict__ w1, const float* __restrict__ b1,
                       const float* __restrict__ w2, const float* __restrict__ b2,
                       void* __restrict__ out, const int* __restrict__ flags)
{
    __shared__ float hs[4][HID];
    __shared__ float t[4][64];
    const int tid = threadIdx.x;
    const int n0 = blockIdx.x * 4;
    for (int i = tid; i < 4*HID; i += 256)
        hs[i >> 7][i & 127] = b2f(hb[(long)n0*HID + i]);
    __syncthreads();
    const int s = tid >> 6, c = tid & 63;
    float acc = b1[c];
    for (int k4 = 0; k4 < 32; ++k4) {
        int k = k4*4;
        float wa = w1[(k+0)*64 + c];
        float wb = w1[(k+1)*64 + c];
        float wc = w1[(k+2)*64 + c];
        float wd = w1[(k+3)*64 + c];
        float4 v = *(const float4*)&hs[s][k];
        acc += v.x*wa + v.y*wb + v.z*wc + v.w*wd;
    }
    t[s][c] = siluf(acc);
    __syncthreads();
    if (c < 3) {
        float a2 = b2[c];
        #pragma unroll
        for (int k = 0; k < 64; ++k) a2 += t[s][k] * w2[k*3 + c];
        int n = n0 + s;
        float v = pos[n*3+c] + a2;
        if (flags[0]) ((__hip_bfloat16*)out)[n*3+c] = __float2bfloat16(v);
        else          ((float*)out)[n*3+c] = v;
    }
}

// ---------------------------------------------------------------------------
extern "C" void kernel_launch(void* const* d_in, const int* in_sizes, int n_in,
                              void* d_out, int out_size, void* d_ws, size_t ws_size,
                              hipStream_t stream)
{
    (void)in_sizes; (void)n_in; (void)out_size; (void)ws_size;

    int* flags = (int*)d_ws;
    float* base = (float*)d_ws;
    size_t off = 64;
    auto alloc = [&](size_t n) { float* p = base + off; off += (n + 63) & ~63ull; return p; };

    static const int aidx[24] = {0,1,3,4,5,6,7,8,9,10,11,12,13,14,15,16,17,18,19,20,21,22,23,24};
    static const int alen[24] = {
        BB*LAT, NN*AF, NA*3, LAT*HID, HID, AF*HID, HID,
        NL*257*HID, NL*HID, NL*HID*HID, NL*HID,
        NL*256*HID, NL*HID, NL*HID*HID, NL*HID,
        NL*HID*HID, NL*HID, NL*HID, NL*HID, NL*HID,
        HID*64, 64, 64*3, 3
    };
    CvtDesc cd;
    float* fp[24];
    for (int a = 0; a < 24; ++a) {
        fp[a] = alloc((size_t)alen[a]);
        cd.src[a] = d_in[aidx[a]];
        cd.dst[a] = fp[a];
        cd.len[a] = alen[a];
    }
    float* agg = alloc((size_t)NN*HID);
    float* hz  = alloc((size_t)BB*HID);
    float* pos = alloc((size_t)NN*3);
    float* upd = alloc((size_t)NN*3);
    short* hb  = (short*)alloc((size_t)NN*HID/2);
    short* H1  = (short*)alloc((size_t)NN*256/2);
    short* wcatp = (short*)alloc((size_t)NL*32768/2);
    short* w2p = (short*)alloc((size_t)NL*16384/2);
    short* c1p = (short*)alloc((size_t)NL*16384/2);
    short* nw1p = (short*)alloc((size_t)NL*32768/2);
    short* nw2p = (short*)alloc((size_t)NL*16384/2);
    int* cnt      = (int*)alloc((size_t)NN);
    int* rowStart = (int*)alloc((size_t)NN + 1);
    int* cursor   = (int*)alloc((size_t)NN);
    int* rS       = (int*)alloc((size_t)NE);
    int* cS       = (int*)alloc((size_t)NE);
    float* relX   = alloc((size_t)NE);
    float* relY   = alloc((size_t)NE);
    float* relZ   = alloc((size_t)NE);
    float* d2S    = alloc((size_t)NE);
    const int* eidx = (const int*)d_in[2];

    k_detect<<<1, 256, 0, stream>>>((const unsigned short*)d_in[0],
                                    (const unsigned int*)d_in[2], flags);
    k_convert<<<dim3((NN*AF + 255)/256, 24), 256, 0, stream>>>(cd, flags);

    PackJobs pj;
    for (int l = 0; l < NL; ++l) {
        int b5 = l*5;
        pj.src[b5+0] = fp[7]  + (size_t)l*257*HID; pj.dst[b5+0] = wcatp + (size_t)l*32768; pj.K[b5+0] = 256; pj.mode[b5+0] = 1;
        pj.src[b5+1] = fp[9]  + (size_t)l*HID*HID; pj.dst[b5+1] = w2p   + (size_t)l*16384; pj.K[b5+1] = 128; pj.mode[b5+1] = 0;
        pj.src[b5+2] = fp[15] + (size_t)l*HID*HID; pj.dst[b5+2] = c1p   + (size_t)l*16384; pj.K[b5+2] = 128; pj.mode[b5+2] = 0;
        pj.src[b5+3] = fp[11] + (size_t)l*256*HID; pj.dst[b5+3] = nw1p  + (size_t)l*32768; pj.K[b5+3] = 256; pj.mode[b5+3] = 0;
        pj.src[b5+4] = fp[13] + (size_t)l*HID*HID; pj.dst[b5+4] = nw2p  + (size_t)l*16384; pj.K[b5+4] = 128; pj.mode[b5+4] = 0;
    }
    k_packall<<<dim3(128, 10), 256, 0, stream>>>(pj);

    // counting sort edges by row
    k_zero_cnt<<<(NN + 255)/256, 256, 0, stream>>>(cnt);
    k_hist<<<(NE + 255)/256, 256, 0, stream>>>(eidx, flags, cnt);
    k_scan<<<1, 1024, 0, stream>>>(cnt, rowStart, cursor);
    k_scatter<<<(NE + 255)/256, 256, 0, stream>>>(eidx, flags, cursor, rS, cS);

    k_hz<<<BB, HID, 0, stream>>>(fp[0], fp[3], fp[4], hz);
    k_init2<<<NN, HID, 0, stream>>>(hz, fp[1], fp[5], fp[6], fp[2], pos, hb);

    for (int l = 0; l < NL; ++l) {
        k_gz<<<(NE + 255)/256, 256, 0, stream>>>(rS, cS, pos,
                                                 relX, relY, relZ, d2S, agg, upd);
        k_pre<<<NN/64, 256, 0, stream>>>(hb, wcatp + (size_t)l*32768,
                                         fp[8] + (size_t)l*HID, H1);
        k_edge4<<<PBLK, 256, 0, stream>>>(H1, rS, cS, relX, relY, relZ, d2S,
            fp[7] + (size_t)l*257*HID + 256*HID,       // w1c (d2 row, f32)
            w2p + (size_t)l*16384, fp[10] + (size_t)l*HID,
            c1p + (size_t)l*16384, fp[16] + (size_t)l*HID,
            fp[17] + (size_t)l*HID,
            agg, upd);
        k_node_mfma<<<NN/64, 256, 0, stream>>>(hb, agg,
            nw1p + (size_t)l*32768, fp[12] + (size_t)l*HID,
            nw2p + (size_t)l*16384, fp[14] + (size_t)l*HID,
            fp[18] + (size_t)l*HID, fp[19] + (size_t)l*HID,
            pos, upd, rowStart);
    }
    k_head<<<NN/4, 256, 0, stream>>>(hb, pos, fp[20], fp[21], fp[22], fp[23],
                                     d_out, flags);
}

// Round 8
// 698.305 us; speedup vs baseline: 1.0624x; 1.0432x over previous
//
#include <hip/hip_runtime.h>
#include <hip/hip_bf16.h>

#define BB 512
#define NA 58
#define LAT 64
#define HID 128
#define AF 10
#define NL 2
#define NN (BB*NA)      // 29696
#define NE (NN*16)      // 475136
#define ET 64           // edges per tile
#define NTILE (NE/ET)   // 7424
#define PBLK 1024       // persistent blocks (4 per CU)

typedef __attribute__((ext_vector_type(8))) short s8;
typedef __attribute__((ext_vector_type(4))) float f4;

struct CvtDesc {
    const void* src[24];
    float*      dst[24];
    int         len[24];
};

struct PackJobs {
    const float* src[10];
    short*       dst[10];
    int          K[10];
    int          mode[10];
};

__device__ __forceinline__ float siluf(float x) {
    return x * __builtin_amdgcn_rcpf(1.0f + __expf(-x));
}

__device__ __forceinline__ short f2b(float x) {
    __hip_bfloat16 b = __float2bfloat16(x);
    return *(short*)&b;
}

__device__ __forceinline__ float b2f(short s) {
    return __uint_as_float(((unsigned int)(unsigned short)s) << 16);
}

// ---------------------------------------------------------------------------
__global__ void k_detect(const unsigned short* __restrict__ z16,
                         const unsigned int* __restrict__ e32,
                         int* __restrict__ flags) {
    __shared__ int sbf, si64;
    if (threadIdx.x == 0) { sbf = 0; si64 = 0; }
    __syncthreads();
    int c1 = 0, c2 = 0;
    for (int i = threadIdx.x; i < 1024; i += 256) {
        unsigned short v = z16[2*i];
        int e = (v >> 7) & 0xFF;
        if (e >= 100 && e <= 140) c1++;
        if (e32[2*i + 1] == 0u) c2++;
    }
    atomicAdd(&sbf, c1);
    atomicAdd(&si64, c2);
    __syncthreads();
    if (threadIdx.x == 0) {
        flags[0] = (sbf  > 600) ? 1 : 0;
        flags[1] = (si64 > 600) ? 1 : 0;
    }
}

__global__ void k_convert(CvtDesc d, const int* __restrict__ flags) {
    int a = blockIdx.y;
    int i = blockIdx.x * blockDim.x + threadIdx.x;
    int n = d.len[a];
    if (i >= n) return;
    if (flags[0]) {
        d.dst[a][i] = __bfloat162float(((const __hip_bfloat16*)d.src[a])[i]);
    } else {
        d.dst[a][i] = ((const float*)d.src[a])[i];
    }
}

__global__ void k_packall(PackJobs pj) {
    int j = blockIdx.y;
    int idx = blockIdx.x * 256 + threadIdx.x;
    const float* w = pj.src[j];
    short* o = pj.dst[j];
    if (pj.mode[j] == 0) {
        int K = pj.K[j];
        if (idx >= 128*K) return;
        int jj = idx & 7;
        int l  = (idx >> 3) & 63;
        int rest = idx >> 9;
        int KC = K >> 5;
        int kc = rest % KC;
        int nt = rest / KC;
        int n = nt*16 + (l & 15);
        int k = kc*32 + (l >> 4)*8 + jj;
        o[idx] = f2b(w[k*128 + n]);
    } else {
        if (idx >= 32768) return;
        int jj = idx & 7;
        int l  = (idx >> 3) & 63;
        int rest = idx >> 9;
        int kc = rest & 3;
        int nt = rest >> 2;
        int n = nt*16 + (l & 15);
        int k = kc*32 + (l >> 4)*8 + jj;
        float v = (n < 128) ? w[k*128 + n] : w[(128 + k)*128 + (n - 128)];
        o[idx] = f2b(v);
    }
}

// ---------------------------------------------------------------------------
// counting sort of edges by row
__global__ void k_zero_cnt(int* __restrict__ cnt) {
    int i = blockIdx.x * 256 + threadIdx.x;
    if (i < NN) cnt[i] = 0;
}

__global__ void k_hist(const int* __restrict__ eidx, const int* __restrict__ flags,
                       int* __restrict__ cnt) {
    int e = blockIdx.x * 256 + threadIdx.x;
    if (e >= NE) return;
    int is64 = flags[1];
    int r = eidx[is64 ? 2*(long)e : (long)e];
    atomicAdd(&cnt[r], 1);
}

__global__ __launch_bounds__(1024) void k_scan(const int* __restrict__ cnt,
                                               int* __restrict__ rowStart,
                                               int* __restrict__ cursor) {
    __shared__ int part[1024];
    int t = threadIdx.x;
    int base = t * 29;                    // NN == 1024*29
    int loc[29];
    int s = 0;
    #pragma unroll
    for (int i = 0; i < 29; ++i) { loc[i] = s; s += cnt[base + i]; }
    part[t] = s;
    __syncthreads();
    for (int d = 1; d < 1024; d <<= 1) {
        int v = (t >= d) ? part[t - d] : 0;
        __syncthreads();
        part[t] += v;
        __syncthreads();
    }
    int pre = (t == 0) ? 0 : part[t - 1];
    #pragma unroll
    for (int i = 0; i < 29; ++i) {
        int v = pre + loc[i];
        rowStart[base + i] = v;
        cursor[base + i] = v;
    }
    if (t == 1023) rowStart[NN] = pre + s;
}

__global__ void k_scatter(const int* __restrict__ eidx, const int* __restrict__ flags,
                          int* __restrict__ cursor,
                          int* __restrict__ rS, int* __restrict__ cS) {
    int e = blockIdx.x * 256 + threadIdx.x;
    if (e >= NE) return;
    int is64 = flags[1];
    long ge = e, gc = (long)e + NE;
    int r = eidx[is64 ? 2*ge : ge];
    int c = eidx[is64 ? 2*gc : gc];
    int p = atomicAdd(&cursor[r], 1);
    rS[p] = r; cS[p] = c;
}

// ---------------------------------------------------------------------------
__global__ void k_hz(const float* __restrict__ z, const float* __restrict__ lw,
                     const float* __restrict__ lb, float* __restrict__ hz) {
    __shared__ float zs[LAT];
    int b = blockIdx.x;
    int c = threadIdx.x;
    if (c < LAT) zs[c] = z[b*LAT + c];
    __syncthreads();
    float acc = lb[c];
    #pragma unroll
    for (int k = 0; k < LAT; ++k) acc += zs[k] * lw[k*HID + c];
    hz[b*HID + c] = acc;
}

__global__ void k_init2(const float* __restrict__ hz, const float* __restrict__ at,
                        const float* __restrict__ aw, const float* __restrict__ ab,
                        const float* __restrict__ ic,
                        float* __restrict__ pos, short* __restrict__ hb) {
    __shared__ float ats[AF];
    int n = blockIdx.x;
    int c = threadIdx.x;
    int b = n / NA;
    if (c < AF) ats[c] = at[n*AF + c];
    __syncthreads();
    float acc = hz[b*HID + c] + ab[c];
    #pragma unroll
    for (int f = 0; f < AF; ++f) acc += ats[f] * aw[f*HID + c];
    hb[(long)n*HID + c] = f2b(acc);
    if (c < 3) {
        int a = n % NA;
        pos[n*3 + c] = ic[a*3 + c];
    }
}

// per-layer: edge geometry planes + zero agg/upd (fused)
__global__ void k_gz(const int* __restrict__ rS, const int* __restrict__ cS,
                     const float* __restrict__ pos,
                     float* __restrict__ relX, float* __restrict__ relY,
                     float* __restrict__ relZ, float* __restrict__ d2S,
                     float* __restrict__ agg, float* __restrict__ upd) {
    int i = blockIdx.x * 256 + threadIdx.x;      // grid covers NE exactly
    if (i < NE) {
        int r = rS[i], c = cS[i];
        float rx = pos[r*3+0] - pos[c*3+0];
        float ry = pos[r*3+1] - pos[c*3+1];
        float rz = pos[r*3+2] - pos[c*3+2];
        relX[i] = rx; relY[i] = ry; relZ[i] = rz;
        d2S[i] = fminf(fmaxf(rx*rx + ry*ry + rz*rz, 1e-6f), 1e6f);
    }
    f4* a4 = (f4*)agg;
    for (long j = i; j < (long)NN*HID/4; j += (long)gridDim.x*256) a4[j] = (f4)0.f;
    if (i < NN*3) upd[i] = 0.f;
}

// ---------------------------------------------------------------------------
// H1 = hb @ [w1a|w1b] (+ b1 on a-half) -> [NN][256] bf16.
__global__ __launch_bounds__(256) void k_pre(
    const short* __restrict__ hb, const short* __restrict__ wcat,
    const float* __restrict__ b1, short* __restrict__ H1)
{
    __shared__ short x[64][136];
    const int tid = threadIdx.x;
    const int n0 = blockIdx.x * 64;

    #pragma unroll
    for (int it = 0; it < 4; ++it) {
        int idx = it*256 + tid;
        int e = idx >> 4, q = idx & 15;
        *(int4*)&x[e][q*8] = *(const int4*)(hb + (long)(n0+e)*HID + q*8);
    }
    __syncthreads();

    const int l = tid & 63, w = tid >> 6;
    const int l16 = l & 15, quad = l >> 4;

    f4 acc[4][4];
    #pragma unroll
    for (int mt = 0; mt < 4; ++mt)
        #pragma unroll
        for (int nt4 = 0; nt4 < 4; ++nt4) acc[mt][nt4] = (f4)0.f;

    #pragma unroll
    for (int kc = 0; kc < 4; ++kc) {
        s8 a[4];
        #pragma unroll
        for (int mt = 0; mt < 4; ++mt)
            a[mt] = *(const s8*)&x[mt*16 + l16][kc*32 + quad*8];
        #pragma unroll
        for (int nt4 = 0; nt4 < 4; ++nt4) {
            int nt = w*4 + nt4;
            s8 b = *(const s8*)(wcat + (((size_t)nt*4 + kc)*64 + l)*8);
            #pragma unroll
            for (int mt = 0; mt < 4; ++mt)
                acc[mt][nt4] = __builtin_amdgcn_mfma_f32_16x16x32_bf16(a[mt], b, acc[mt][nt4], 0, 0, 0);
        }
    }
    #pragma unroll
    for (int nt4 = 0; nt4 < 4; ++nt4) {
        int col = (w*4 + nt4)*16 + l16;
        float bias = (col < 128) ? b1[col] : 0.f;
        #pragma unroll
        for (int mt = 0; mt < 4; ++mt)
            #pragma unroll
            for (int i = 0; i < 4; ++i) {
                int row = mt*16 + quad*4 + i;
                H1[(long)(n0 + row)*256 + col] = f2b(acc[mt][nt4][i] + bias);
            }
    }
}

// ---------------------------------------------------------------------------
// Edge kernel v5: index/d2 prefetched one tile ahead (12 VGPRs), H1 gathers
// issued at loop-top and consumed immediately (no long register residency,
// no scratch spill). 4 barriers, 4 blocks/CU.
__global__ __launch_bounds__(256, 4) void k_edge5(
    const short* __restrict__ H1,
    const int* __restrict__ rS, const int* __restrict__ cS,
    const float* __restrict__ relX, const float* __restrict__ relY,
    const float* __restrict__ relZ, const float* __restrict__ d2S,
    const float* __restrict__ w1c,
    const short* __restrict__ w2p, const float* __restrict__ b2,
    const short* __restrict__ c1p, const float* __restrict__ cb1,
    const float* __restrict__ cw2,
    float* __restrict__ agg, float* __restrict__ upd)
{
    __shared__ short t1[ET][136];
    __shared__ short mm[ET][136];
    __shared__ int   rIs[ET];
    __shared__ float sred[ET];

    const int tid = threadIdx.x;
    const int l = tid & 63, w = tid >> 6;
    const int l16 = l & 15, quad = l >> 4;
    const int c0 = (2*w)*16 + l16, c1c = (2*w+1)*16 + l16;
    const int half = tid >> 7, ch = tid & 127;
    const int q = tid & 15;          // fixed channel chunk
    const int esub = tid >> 4;       // edge subgroup 0..15

    float wv[8];
    #pragma unroll
    for (int j = 0; j < 8; ++j) wv[j] = w1c[q*8 + j];

    s8 w2f[8], c1f[8];
    #pragma unroll
    for (int kc = 0; kc < 4; ++kc) {
        w2f[kc]     = *(const s8*)(w2p + (((size_t)(2*w)*4 + kc)*64 + l)*8);
        w2f[4 + kc] = *(const s8*)(w2p + (((size_t)(2*w+1)*4 + kc)*64 + l)*8);
        c1f[kc]     = *(const s8*)(c1p + (((size_t)(2*w)*4 + kc)*64 + l)*8);
        c1f[4 + kc] = *(const s8*)(c1p + (((size_t)(2*w+1)*4 + kc)*64 + l)*8);
    }
    const float bia2_0 = b2[c0],  bia2_1 = b2[c1c];
    const float biac_0 = cb1[c0], biac_1 = cb1[c1c];
    const float cw0    = cw2[c0], cw1v   = cw2[c1c];

    // lightweight prefetch: indices + d2 for this thread's 4 edges
    int   pri[4], pci[4];
    float pd2[4];

    auto PREIDX = [&](int T) {
        long eb = (long)T * ET;
        #pragma unroll
        for (int it = 0; it < 4; ++it) {
            int e = esub + 16*it;
            pri[it] = rS[eb + e];
            pci[it] = cS[eb + e];
            pd2[it] = d2S[eb + e];
        }
    };

    int t = blockIdx.x;
    if (t < NTILE) PREIDX(t);

    while (t < NTILE) {
        // issue H1 gathers now (global loads, no LDS dep) — drain at (A)
        s8 va[4], vb[4];
        #pragma unroll
        for (int it = 0; it < 4; ++it) {
            va[it] = *(const s8*)(H1 + (long)pri[it]*256 + q*8);
            vb[it] = *(const s8*)(H1 + (long)pci[it]*256 + 128 + q*8);
        }
        __syncthreads();                 // (A) previous tile fully consumed
        if (tid < ET) sred[tid] = 0.f;
        if (q == 0) {
            #pragma unroll
            for (int it = 0; it < 4; ++it) rIs[esub + 16*it] = pri[it];
        }
        // build t1 from gathered regs
        #pragma unroll
        for (int it = 0; it < 4; ++it) {
            int e = esub + 16*it;
            float d2 = pd2[it];
            s8 o;
            #pragma unroll
            for (int j = 0; j < 8; ++j) {
                float v = b2f(va[it][j]) + b2f(vb[it][j]) + d2*wv[j];
                o[j] = f2b(siluf(v));
            }
            *(s8*)&t1[e][q*8] = o;
        }
        __syncthreads();                 // (B) t1 + meta ready

        int tn = t + PBLK;
        if (tn < NTILE) PREIDX(tn);      // 12 cheap loads, drain over stages

        // ---- stage 2: m = silu(t1 @ w2 + b2) -> mm bf16
        {
            f4 acc[4][2];
            #pragma unroll
            for (int mt = 0; mt < 4; ++mt) { acc[mt][0] = (f4)0.f; acc[mt][1] = (f4)0.f; }
            #pragma unroll
            for (int kc = 0; kc < 4; ++kc) {
                #pragma unroll
                for (int mt = 0; mt < 4; ++mt) {
                    s8 a = *(const s8*)&t1[mt*16 + l16][kc*32 + quad*8];
                    acc[mt][0] = __builtin_amdgcn_mfma_f32_16x16x32_bf16(a, w2f[kc],     acc[mt][0], 0, 0, 0);
                    acc[mt][1] = __builtin_amdgcn_mfma_f32_16x16x32_bf16(a, w2f[4 + kc], acc[mt][1], 0, 0, 0);
                }
            }
            #pragma unroll
            for (int mt = 0; mt < 4; ++mt) {
                #pragma unroll
                for (int i = 0; i < 4; ++i) {
                    int row = mt*16 + quad*4 + i;
                    mm[row][c0]  = f2b(siluf(acc[mt][0][i] + bia2_0));
                    mm[row][c1c] = f2b(siluf(acc[mt][1][i] + bia2_1));
                }
            }
        }
        __syncthreads();                 // (C) mm ready

        // ---- stage 3: c1 = silu(mm @ cw1 + cb1); dot cw2 -> sred
        {
            f4 acc[4][2];
            #pragma unroll
            for (int mt = 0; mt < 4; ++mt) { acc[mt][0] = (f4)0.f; acc[mt][1] = (f4)0.f; }
            #pragma unroll
            for (int kc = 0; kc < 4; ++kc) {
                #pragma unroll
                for (int mt = 0; mt < 4; ++mt) {
                    s8 a = *(const s8*)&mm[mt*16 + l16][kc*32 + quad*8];
                    acc[mt][0] = __builtin_amdgcn_mfma_f32_16x16x32_bf16(a, c1f[kc],     acc[mt][0], 0, 0, 0);
                    acc[mt][1] = __builtin_amdgcn_mfma_f32_16x16x32_bf16(a, c1f[4 + kc], acc[mt][1], 0, 0, 0);
                }
            }
            #pragma unroll
            for (int mt = 0; mt < 4; ++mt) {
                #pragma unroll
                for (int i = 0; i < 4; ++i) {
                    float p = siluf(acc[mt][0][i] + biac_0) * cw0
                            + siluf(acc[mt][1][i] + biac_1) * cw1v;
                    p += __shfl_xor(p, 1);
                    p += __shfl_xor(p, 2);
                    p += __shfl_xor(p, 4);
                    p += __shfl_xor(p, 8);
                    if (l16 == 0) {
                        int row = mt*16 + quad*4 + i;
                        atomicAdd(&sred[row], p);
                    }
                }
            }
        }

        // ---- segmented agg reduction over sorted rows (reads mm bf16)
        {
            int e0 = half * 32;
            int cur = rIs[e0];
            float a = 0.f;
            #pragma unroll
            for (int e = e0; e < e0 + 32; ++e) {
                int r = rIs[e];
                if (r != cur) {
                    atomicAdd(&agg[(long)cur*HID + ch], a);
                    a = 0.f; cur = r;
                }
                a += b2f(mm[e][ch]);
            }
            atomicAdd(&agg[(long)cur*HID + ch], a);
        }
        __syncthreads();                 // (D) sred complete

        if (tid < ET) {
            long ge = (long)t*ET + tid;
            float cwv = fminf(fmaxf(sred[tid], -1.f), 1.f);
            int r = rIs[tid];
            atomicAdd(&upd[r*3+0], cwv*relX[ge]);
            atomicAdd(&upd[r*3+1], cwv*relY[ge]);
            atomicAdd(&upd[r*3+2], cwv*relZ[ge]);
        }
        t = tn;
    }
}

// ---------------------------------------------------------------------------
__global__ __launch_bounds__(256) void k_node_mfma(
    short* __restrict__ hb, const float* __restrict__ agg,
    const short* __restrict__ w1p, const float* __restrict__ b1n,
    const short* __restrict__ w2p, const float* __restrict__ b2n,
    const float* __restrict__ lg, const float* __restrict__ lb,
    float* __restrict__ pos, const float* __restrict__ upd,
    const int* __restrict__ rowStart)
{
    __shared__ short x[64][264];
    __shared__ short t1[64][144];
    __shared__ float mus[64], rstds[64];
    float (*hn)[132] = (float (*)[132])&x[0][0];

    const int tid = threadIdx.x;
    const int n0 = blockIdx.x * 64;

    #pragma unroll
    for (int it = 0; it < 4; ++it) {
        int idx = it*256 + tid;
        int e = idx >> 4, q = idx & 15;
        *(int4*)&x[e][q*8] = *(const int4*)(hb + (long)(n0+e)*HID + q*8);
    }
    #pragma unroll
    for (int it = 0; it < 8; ++it) {
        int idx = it*256 + tid;
        int e = idx >> 5, q = idx & 31;
        float4 v = *(const float4*)(agg + (long)(n0+e)*HID + q*4);
        short4 sv;
        sv.x = f2b(v.x); sv.y = f2b(v.y); sv.z = f2b(v.z); sv.w = f2b(v.w);
        *(short4*)&x[e][128 + q*4] = sv;
    }
    __syncthreads();

    const int l = tid & 63, w = tid >> 6;
    const int l16 = l & 15, quad = l >> 4;
    const int nt0 = 2*w, nt1 = 2*w + 1;
    const int c0 = nt0*16 + l16, c1c = nt1*16 + l16;

    {
        f4 acc[4][2];
        #pragma unroll
        for (int mt = 0; mt < 4; ++mt) { acc[mt][0] = (f4)0.f; acc[mt][1] = (f4)0.f; }
        #pragma unroll
        for (int kc = 0; kc < 8; ++kc) {
            s8 b0  = *(const s8*)(w1p + (((size_t)nt0*8 + kc)*64 + l)*8);
            s8 b1f = *(const s8*)(w1p + (((size_t)nt1*8 + kc)*64 + l)*8);
            #pragma unroll
            for (int mt = 0; mt < 4; ++mt) {
                s8 a = *(const s8*)&x[mt*16 + l16][kc*32 + quad*8];
                acc[mt][0] = __builtin_amdgcn_mfma_f32_16x16x32_bf16(a, b0,  acc[mt][0], 0, 0, 0);
                acc[mt][1] = __builtin_amdgcn_mfma_f32_16x16x32_bf16(a, b1f, acc[mt][1], 0, 0, 0);
            }
        }
        float bia0 = b1n[c0], bia1 = b1n[c1c];
        #pragma unroll
        for (int mt = 0; mt < 4; ++mt) {
            #pragma unroll
            for (int i = 0; i < 4; ++i) {
                int row = mt*16 + quad*4 + i;
                t1[row][c0]  = f2b(siluf(acc[mt][0][i] + bia0));
                t1[row][c1c] = f2b(siluf(acc[mt][1][i] + bia1));
            }
        }
    }
    __syncthreads();

    {
        f4 acc[4][2];
        #pragma unroll
        for (int mt = 0; mt < 4; ++mt) { acc[mt][0] = (f4)0.f; acc[mt][1] = (f4)0.f; }
        #pragma unroll
        for (int kc = 0; kc < 4; ++kc) {
            s8 b0  = *(const s8*)(w2p + (((size_t)nt0*4 + kc)*64 + l)*8);
            s8 b1f = *(const s8*)(w2p + (((size_t)nt1*4 + kc)*64 + l)*8);
            #pragma unroll
            for (int mt = 0; mt < 4; ++mt) {
                s8 a = *(const s8*)&t1[mt*16 + l16][kc*32 + quad*8];
                acc[mt][0] = __builtin_amdgcn_mfma_f32_16x16x32_bf16(a, b0,  acc[mt][0], 0, 0, 0);
                acc[mt][1] = __builtin_amdgcn_mfma_f32_16x16x32_bf16(a, b1f, acc[mt][1], 0, 0, 0);
            }
        }
        float bia0 = b2n[c0], bia1 = b2n[c1c];
        __syncthreads();
        #pragma unroll
        for (int mt = 0; mt < 4; ++mt) {
            #pragma unroll
            for (int i = 0; i < 4; ++i) {
                int row = mt*16 + quad*4 + i;
                hn[row][c0]  = acc[mt][0][i] + bia0;
                hn[row][c1c] = acc[mt][1][i] + bia1;
            }
        }
    }
    __syncthreads();

    {
        int r = tid >> 2, part = tid & 3;
        float s = 0.f, q = 0.f;
        #pragma unroll
        for (int j = 0; j < 32; ++j) {
            float v = hn[r][part + 4*j];
            s += v; q += v*v;
        }
        s += __shfl_xor(s, 1); q += __shfl_xor(q, 1);
        s += __shfl_xor(s, 2); q += __shfl_xor(q, 2);
        if (part == 0) {
            float mu = s * (1.0f/HID);
            float var = q * (1.0f/HID) - mu*mu;
            mus[r] = mu;
            rstds[r] = rsqrtf(var + 1e-5f);
        }
    }
    __syncthreads();

    #pragma unroll
    for (int it = 0; it < 32; ++it) {
        int idx = it*256 + tid;
        int r = idx >> 7, c = idx & 127;
        float v = (hn[r][c] - mus[r]) * rstds[r] * lg[c] + lb[c];
        hb[(long)(n0 + r)*HID + c] = f2b(v);
    }
    if (tid < 192) {
        int i = tid / 3, d = tid - i*3;
        int n = n0 + i;
        float dg = (float)(rowStart[n+1] - rowStart[n]);
        pos[n*3+d] += upd[n*3+d] / (dg + 1e-6f);
    }
}

// ---------------------------------------------------------------------------
__global__ void k_head(const short* __restrict__ hb, const float* __restrict__ pos,
                       const float* __restrict__ w1, const float* __restrict__ b1,
                       const float* __restrict__ w2, const float* __restrict__ b2,
                       void* __restrict__ out, const int* __restrict__ flags)
{
    __shared__ float hs[4][HID];
    __shared__ float t[4][64];
    const int tid = threadIdx.x;
    const int n0 = blockIdx.x * 4;
    for (int i = tid; i < 4*HID; i += 256)
        hs[i >> 7][i & 127] = b2f(hb[(long)n0*HID + i]);
    __syncthreads();
    const int s = tid >> 6, c = tid & 63;
    float acc = b1[c];
    for (int k4 = 0; k4 < 32; ++k4) {
        int k = k4*4;
        float wa = w1[(k+0)*64 + c];
        float wb = w1[(k+1)*64 + c];
        float wc = w1[(k+2)*64 + c];
        float wd = w1[(k+3)*64 + c];
        float4 v = *(const float4*)&hs[s][k];
        acc += v.x*wa + v.y*wb + v.z*wc + v.w*wd;
    }
    t[s][c] = siluf(acc);
    __syncthreads();
    if (c < 3) {
        float a2 = b2[c];
        #pragma unroll
        for (int k = 0; k < 64; ++k) a2 += t[s][k] * w2[k*3 + c];
        int n = n0 + s;
        float v = pos[n*3+c] + a2;
        if (flags[0]) ((__hip_bfloat16*)out)[n*3+c] = __float2bfloat16(v);
        else          ((float*)out)[n*3+c] = v;
    }
}

// ---------------------------------------------------------------------------
extern "C" void kernel_launch(void* const* d_in, const int* in_sizes, int n_in,
                              void* d_out, int out_size, void* d_ws, size_t ws_size,
                              hipStream_t stream)
{
    (void)in_sizes; (void)n_in; (void)out_size; (void)ws_size;

    int* flags = (int*)d_ws;
    float* base = (float*)d_ws;
    size_t off = 64;
    auto alloc = [&](size_t n) { float* p = base + off; off += (n + 63) & ~63ull; return p; };

    static const int aidx[24] = {0,1,3,4,5,6,7,8,9,10,11,12,13,14,15,16,17,18,19,20,21,22,23,24};
    static const int alen[24] = {
        BB*LAT, NN*AF, NA*3, LAT*HID, HID, AF*HID, HID,
        NL*257*HID, NL*HID, NL*HID*HID, NL*HID,
        NL*256*HID, NL*HID, NL*HID*HID, NL*HID,
        NL*HID*HID, NL*HID, NL*HID, NL*HID, NL*HID,
        HID*64, 64, 64*3, 3
    };
    CvtDesc cd;
    float* fp[24];
    for (int a = 0; a < 24; ++a) {
        fp[a] = alloc((size_t)alen[a]);
        cd.src[a] = d_in[aidx[a]];
        cd.dst[a] = fp[a];
        cd.len[a] = alen[a];
    }
    float* agg = alloc((size_t)NN*HID);
    float* hz  = alloc((size_t)BB*HID);
    float* pos = alloc((size_t)NN*3);
    float* upd = alloc((size_t)NN*3);
    short* hb  = (short*)alloc((size_t)NN*HID/2);
    short* H1  = (short*)alloc((size_t)NN*256/2);
    short* wcatp = (short*)alloc((size_t)NL*32768/2);
    short* w2p = (short*)alloc((size_t)NL*16384/2);
    short* c1p = (short*)alloc((size_t)NL*16384/2);
    short* nw1p = (short*)alloc((size_t)NL*32768/2);
    short* nw2p = (short*)alloc((size_t)NL*16384/2);
    int* cnt      = (int*)alloc((size_t)NN);
    int* rowStart = (int*)alloc((size_t)NN + 1);
    int* cursor   = (int*)alloc((size_t)NN);
    int* rS       = (int*)alloc((size_t)NE);
    int* cS       = (int*)alloc((size_t)NE);
    float* relX   = alloc((size_t)NE);
    float* relY   = alloc((size_t)NE);
    float* relZ   = alloc((size_t)NE);
    float* d2S    = alloc((size_t)NE);
    const int* eidx = (const int*)d_in[2];

    k_detect<<<1, 256, 0, stream>>>((const unsigned short*)d_in[0],
                                    (const unsigned int*)d_in[2], flags);
    k_convert<<<dim3((NN*AF + 255)/256, 24), 256, 0, stream>>>(cd, flags);

    PackJobs pj;
    for (int l = 0; l < NL; ++l) {
        int b5 = l*5;
        pj.src[b5+0] = fp[7]  + (size_t)l*257*HID; pj.dst[b5+0] = wcatp + (size_t)l*32768; pj.K[b5+0] = 256; pj.mode[b5+0] = 1;
        pj.src[b5+1] = fp[9]  + (size_t)l*HID*HID; pj.dst[b5+1] = w2p   + (size_t)l*16384; pj.K[b5+1] = 128; pj.mode[b5+1] = 0;
        pj.src[b5+2] = fp[15] + (size_t)l*HID*HID; pj.dst[b5+2] = c1p   + (size_t)l*16384; pj.K[b5+2] = 128; pj.mode[b5+2] = 0;
        pj.src[b5+3] = fp[11] + (size_t)l*256*HID; pj.dst[b5+3] = nw1p  + (size_t)l*32768; pj.K[b5+3] = 256; pj.mode[b5+3] = 0;
        pj.src[b5+4] = fp[13] + (size_t)l*HID*HID; pj.dst[b5+4] = nw2p  + (size_t)l*16384; pj.K[b5+4] = 128; pj.mode[b5+4] = 0;
    }
    k_packall<<<dim3(128, 10), 256, 0, stream>>>(pj);

    // counting sort edges by row
    k_zero_cnt<<<(NN + 255)/256, 256, 0, stream>>>(cnt);
    k_hist<<<(NE + 255)/256, 256, 0, stream>>>(eidx, flags, cnt);
    k_scan<<<1, 1024, 0, stream>>>(cnt, rowStart, cursor);
    k_scatter<<<(NE + 255)/256, 256, 0, stream>>>(eidx, flags, cursor, rS, cS);

    k_hz<<<BB, HID, 0, stream>>>(fp[0], fp[3], fp[4], hz);
    k_init2<<<NN, HID, 0, stream>>>(hz, fp[1], fp[5], fp[6], fp[2], pos, hb);

    for (int l = 0; l < NL; ++l) {
        k_gz<<<(NE + 255)/256, 256, 0, stream>>>(rS, cS, pos,
                                                 relX, relY, relZ, d2S, agg, upd);
        k_pre<<<NN/64, 256, 0, stream>>>(hb, wcatp + (size_t)l*32768,
                                         fp[8] + (size_t)l*HID, H1);
        k_edge5<<<PBLK, 256, 0, stream>>>(H1, rS, cS, relX, relY, relZ, d2S,
            fp[7] + (size_t)l*257*HID + 256*HID,       // w1c (d2 row, f32)
            w2p + (size_t)l*16384, fp[10] + (size_t)l*HID,
            c1p + (size_t)l*16384, fp[16] + (size_t)l*HID,
            fp[17] + (size_t)l*HID,
            agg, upd);
        k_node_mfma<<<NN/64, 256, 0, stream>>>(hb, agg,
            nw1p + (size_t)l*32768, fp[12] + (size_t)l*HID,
            nw2p + (size_t)l*16384, fp[14] + (size_t)l*HID,
            fp[18] + (size_t)l*HID, fp[19] + (size_t)l*HID,
            pos, upd, rowStart);
    }
    k_head<<<NN/4, 256, 0, stream>>>(hb, pos, fp[20], fp[21], fp[22], fp[23],
                                     d_out, flags);
}